// Round 1
// baseline (772.079 us; speedup 1.0000x reference)
//
#include <hip/hip_runtime.h>
#include <stdint.h>

// L2 1-NN: B=4096 queries x[B,256] vs N=32768 prototypes P[N,256], fp32.
// argmin_j (psq[j] - 2*x.p_j)  (x_sq drops out of argmin), then gather P[idx].
//
// Round 1: exact-fp32 baseline. Fused tiled GEMM + argmin.
//   ws layout: [0, NP*4) psq  |  [NP*4, NP*4 + NB*8) packed (key<<32|idx) u64
//   key = monotone-uint transform of fp32 distance -> u64 atomicMin gives
//   global min with smallest index on exact ties (matches np.argmin).

#define NB 4096
#define NP 32768
#define ND 256

#define BM 128
#define BN 128
#define BK 32
#define LDA 132   // padded row (floats) for K-transposed tiles; 528B, 16B-aligned

// ---------------------------------------------------------------- psq + init
__global__ void psq_init_kernel(const float* __restrict__ P,
                                float* __restrict__ psq,
                                unsigned long long* __restrict__ minpack) {
    int row  = blockIdx.x * 4 + (threadIdx.x >> 6);   // 4 waves/block, 1 row/wave
    int lane = threadIdx.x & 63;
    float4 p4 = ((const float4*)(P + (size_t)row * ND))[lane];
    float s = p4.x*p4.x + p4.y*p4.y + p4.z*p4.z + p4.w*p4.w;
    #pragma unroll
    for (int off = 32; off > 0; off >>= 1) s += __shfl_down(s, off);
    if (lane == 0) psq[row] = s;
    // init argmin workspace (poisoned 0xAA by harness; must re-init every call)
    int gid = blockIdx.x * blockDim.x + threadIdx.x;
    if (gid < NB) minpack[gid] = 0xFFFFFFFFFFFFFFFFull;
}

// -------------------------------------------------------- fused GEMM + argmin
__global__ __launch_bounds__(256, 2)
void nn_main_kernel(const float* __restrict__ X, const float* __restrict__ P,
                    const float* __restrict__ psq,
                    unsigned long long* __restrict__ minpack) {
    // K-transposed tiles: As[k][row], Bs[k][col]; reused as u64 red[][] in epilogue
    __shared__ __align__(16) char smem_raw[2 * BK * LDA * 4];
    float (*As)[LDA] = (float (*)[LDA])smem_raw;
    float (*Bs)[LDA] = (float (*)[LDA])(smem_raw + BK * LDA * 4);

    const int bm  = blockIdx.y * BM;
    const int bn  = blockIdx.x * BN;
    const int tid = threadIdx.x;
    const int tx  = tid & 15;        // 16 col-thread groups
    const int ty  = tid >> 4;        // 16 row-thread groups

    float acc[8][8];
    #pragma unroll
    for (int i = 0; i < 8; ++i)
        #pragma unroll
        for (int j = 0; j < 8; ++j) acc[i][j] = 0.f;

    const int lrow = tid >> 3;        // 0..31: staging row within pass
    const int lk   = (tid & 7) * 4;   // k sub-offset, float4 granules

    for (int k0 = 0; k0 < ND; k0 += BK) {
        #pragma unroll
        for (int p = 0; p < 4; ++p) {
            int r = p * 32 + lrow;
            float4 a = *(const float4*)(X + (size_t)(bm + r) * ND + k0 + lk);
            As[lk+0][r] = a.x; As[lk+1][r] = a.y; As[lk+2][r] = a.z; As[lk+3][r] = a.w;
            float4 b = *(const float4*)(P + (size_t)(bn + r) * ND + k0 + lk);
            Bs[lk+0][r] = b.x; Bs[lk+1][r] = b.y; Bs[lk+2][r] = b.z; Bs[lk+3][r] = b.w;
        }
        __syncthreads();
        #pragma unroll 4
        for (int k = 0; k < BK; ++k) {
            // rows: 8 contiguous (broadcast across tx, conflict-free)
            float4 a0 = *(const float4*)&As[k][ty*8];
            float4 a1 = *(const float4*)&As[k][ty*8 + 4];
            // cols: split 4+4 so a wave's b-reads span 256B contiguous (2-way = free)
            float4 b0 = *(const float4*)&Bs[k][tx*4];
            float4 b1 = *(const float4*)&Bs[k][64 + tx*4];
            float av[8] = {a0.x,a0.y,a0.z,a0.w,a1.x,a1.y,a1.z,a1.w};
            float bv[8] = {b0.x,b0.y,b0.z,b0.w,b1.x,b1.y,b1.z,b1.w};
            #pragma unroll
            for (int i = 0; i < 8; ++i)
                #pragma unroll
                for (int j = 0; j < 8; ++j)
                    acc[i][j] = fmaf(av[i], bv[j], acc[i][j]);
        }
        __syncthreads();
    }

    // ---- epilogue: dist = psq[j] - 2*dot; per-thread min over 8 cols ----
    unsigned long long (*red)[16] = (unsigned long long (*)[16])smem_raw;
    float cj[8];
    int   jglob[8];
    #pragma unroll
    for (int j = 0; j < 8; ++j) {
        int c = (j < 4) ? (tx*4 + j) : (64 + tx*4 + (j - 4));   // ascending in j
        jglob[j] = bn + c;
        cj[j]    = psq[bn + c];
    }
    #pragma unroll
    for (int i = 0; i < 8; ++i) {
        float best = 0.f; unsigned bidx = 0u; bool first = true;
        #pragma unroll
        for (int j = 0; j < 8; ++j) {
            float s = fmaf(-2.f, acc[i][j], cj[j]);
            if (first || s < best) { best = s; bidx = (unsigned)jglob[j]; first = false; }
        }
        // monotone float->uint key: unsigned order == float order
        unsigned u = __float_as_uint(best);
        u = (u & 0x80000000u) ? ~u : (u | 0x80000000u);
        red[ty*8 + i][tx] = ((unsigned long long)u << 32) | (unsigned long long)bidx;
    }
    __syncthreads();
    if (tid < BM) {
        unsigned long long m = red[tid][0];
        #pragma unroll
        for (int t = 1; t < 16; ++t) {
            unsigned long long v = red[tid][t];
            if (v < m) m = v;
        }
        atomicMin(&minpack[bm + tid], m);   // device-scope: safe cross-XCD
    }
}

// ------------------------------------------------------------------- gather
__global__ void gather_kernel(const float* __restrict__ P,
                              const unsigned long long* __restrict__ minpack,
                              float* __restrict__ out) {
    int row = blockIdx.x;
    unsigned idx = (unsigned)(minpack[row] & 0xFFFFFFFFull);
    int lane = threadIdx.x;   // 64 threads * float4 = 256 floats
    ((float4*)(out + (size_t)row * ND))[lane] =
        ((const float4*)(P + (size_t)idx * ND))[lane];
}

// ------------------------------------------------------------------- launch
extern "C" void kernel_launch(void* const* d_in, const int* in_sizes, int n_in,
                              void* d_out, int out_size, void* d_ws, size_t ws_size,
                              hipStream_t stream) {
    const float* X = (const float*)d_in[0];
    const float* P = (const float*)d_in[1];
    float* out = (float*)d_out;

    float* psq = (float*)d_ws;
    unsigned long long* minpack =
        (unsigned long long*)((char*)d_ws + (size_t)NP * 4);   // needs 160KB ws

    psq_init_kernel<<<NP / 4, 256, 0, stream>>>(P, psq, minpack);

    dim3 grid(NP / BN, NB / BM);   // 256 x 32 = 8192 blocks
    nn_main_kernel<<<grid, dim3(256), 0, stream>>>(X, P, psq, minpack);

    gather_kernel<<<NB, 64, 0, stream>>>(P, minpack, out);
}

// Round 2
// 284.690 us; speedup vs baseline: 2.7120x; 2.7120x over previous
//
#include <hip/hip_runtime.h>
#include <stdint.h>

// L2 1-NN, B=4096 x[B,256] vs N=32768 P[N,256] fp32.
// Round 2: bf16-MFMA screening GEMM + provably-sufficient fp32 margin rescore.
//   argmin_j (psq[j] - 2 x.p_j); x_sq drops out.
// Screening error per distance << MARGIN=3.0, and the block holding the true NN
// always has blockmin <= global_approx_min + 2*err, so rescoring all blocks
// within MARGIN of the approx min in exact fp32 reproduces the exact argmin.

#define NB 4096
#define NP 32768
#define ND 256
#define NBLK 256           // N / 128 column blocks
#define MARGIN 3.0f

typedef __attribute__((ext_vector_type(8))) __bf16 bf16x8;
typedef __attribute__((ext_vector_type(4))) __bf16 bf16x4;
typedef __attribute__((ext_vector_type(4))) float f32x4;

// ---- workspace layout (bytes) ----
static constexpr size_t OFF_PSQ = 0;                               // 32768 f32
static constexpr size_t OFF_XB  = 131072;                          // 4096x256 bf16
static constexpr size_t OFF_PB  = OFF_XB + (size_t)NB * ND * 2;    // 32768x256 bf16
static constexpr size_t OFF_BM  = OFF_PB + (size_t)NP * ND * 2;    // 4096x256 u64
static constexpr size_t WS_NEED = OFF_BM + (size_t)NB * NBLK * 8;  // 27,394,048

__device__ __forceinline__ void gload_lds16(const void* g, void* l) {
    __builtin_amdgcn_global_load_lds(
        (const __attribute__((address_space(1))) uint32_t*)g,
        (__attribute__((address_space(3))) uint32_t*)l, 16, 0, 0);
}
__device__ __forceinline__ unsigned fkey(float f) {
    unsigned u = __float_as_uint(f);
    return (u & 0x80000000u) ? ~u : (u | 0x80000000u);
}
__device__ __forceinline__ float fkey_inv(unsigned u) {
    unsigned o = (u & 0x80000000u) ? (u & 0x7FFFFFFFu) : ~u;
    return __uint_as_float(o);
}
__device__ __forceinline__ unsigned long long umin64(unsigned long long a,
                                                     unsigned long long b) {
    return a < b ? a : b;
}

// ------------------------------------------------- prep: bf16 convert + psq
__global__ void prep_kernel(const float* __restrict__ X, const float* __restrict__ P,
                            float* __restrict__ psq, __bf16* __restrict__ Xb,
                            __bf16* __restrict__ Pb) {
    int row  = blockIdx.x * 4 + (threadIdx.x >> 6);  // one wave per row
    int lane = threadIdx.x & 63;
    if (row < NP) {
        f32x4 v = ((const f32x4*)(P + (size_t)row * ND))[lane];
        bf16x4 b;
        b.x = (__bf16)v.x; b.y = (__bf16)v.y; b.z = (__bf16)v.z; b.w = (__bf16)v.w;
        ((bf16x4*)(Pb + (size_t)row * ND))[lane] = b;
        float s = v.x*v.x + v.y*v.y + v.z*v.z + v.w*v.w;
        #pragma unroll
        for (int off = 32; off > 0; off >>= 1) s += __shfl_down(s, off);
        if (lane == 0) psq[row] = s;
    } else {
        int r = row - NP;   // < NB
        f32x4 v = ((const f32x4*)(X + (size_t)r * ND))[lane];
        bf16x4 b;
        b.x = (__bf16)v.x; b.y = (__bf16)v.y; b.z = (__bf16)v.z; b.w = (__bf16)v.w;
        ((bf16x4*)(Xb + (size_t)r * ND))[lane] = b;
    }
}

// --------------------------------- bf16 MFMA GEMM + per-(row, 128-col-block) min
// LDS layout (lane-linear, conflict-free): tile = [frag(16 rows) x ks(32 k)] units,
// chunk index c = (frag*2 + ks)*64 + lane, lane = kg*16 + fr, element 16B at c*16.
__global__ __launch_bounds__(256)
void nn_bf16_kernel(const __bf16* __restrict__ Xb, const __bf16* __restrict__ Pb,
                    const float* __restrict__ psq,
                    unsigned long long* __restrict__ blockmin) {
    __shared__ __align__(16) char smem[32768];     // As 16KB | Bs 16KB
    __shared__ unsigned long long red[128][2];
    char* As = smem;
    char* Bs = smem + 16384;

    const int tid  = threadIdx.x;
    const int lane = tid & 63;
    const int wave = tid >> 6;
    const int wm = wave >> 1, wn = wave & 1;
    const int bm = blockIdx.y * 128;
    const int bn = blockIdx.x * 128;

    f32x4 acc[4][4];
    #pragma unroll
    for (int i = 0; i < 4; ++i)
        #pragma unroll
        for (int j = 0; j < 4; ++j) acc[i][j] = (f32x4){0.f, 0.f, 0.f, 0.f};

    const int wbase = tid & ~63;   // wave-uniform chunk base within a 256-chunk issue

    for (int k0 = 0; k0 < ND; k0 += 64) {
        #pragma unroll
        for (int i = 0; i < 8; ++i) {              // 4 issues A, 4 issues B
            const bool isB = (i >= 4);
            const int c    = (i & 3) * 256 + tid;  // chunk 0..1023
            const int fmks = c >> 6;               // frag*2 + ks
            const int fm   = fmks >> 1;
            const int ks   = fmks & 1;
            const int lid  = c & 63;
            const int kg   = lid >> 4;
            const int fr   = lid & 15;
            const int kg8  = k0 + ks * 32 + kg * 8;
            const __bf16* src = isB ? (Pb + (size_t)(bn + fm * 16 + fr) * ND + kg8)
                                    : (Xb + (size_t)(bm + fm * 16 + fr) * ND + kg8);
            char* dst = (isB ? Bs : As) + ((size_t)((i & 3) * 256 + wbase)) * 16;
            gload_lds16(src, dst);
        }
        __syncthreads();
        #pragma unroll
        for (int ks = 0; ks < 2; ++ks) {
            bf16x8 a[4], b[4];
            #pragma unroll
            for (int mi = 0; mi < 4; ++mi) {
                int fm = wm * 4 + mi;
                a[mi] = *(const bf16x8*)(As + ((fm * 2 + ks) * 64 + lane) * 16);
            }
            #pragma unroll
            for (int ni = 0; ni < 4; ++ni) {
                int fn = wn * 4 + ni;
                b[ni] = *(const bf16x8*)(Bs + ((fn * 2 + ks) * 64 + lane) * 16);
            }
            #pragma unroll
            for (int mi = 0; mi < 4; ++mi)
                #pragma unroll
                for (int ni = 0; ni < 4; ++ni)
                    acc[mi][ni] = __builtin_amdgcn_mfma_f32_16x16x32_bf16(
                        a[mi], b[ni], acc[mi][ni], 0, 0, 0);
        }
        __syncthreads();
    }

    // epilogue: dist = psq - 2*dot; per-row min over this block's 128 cols
    const int cl = lane & 15;      // C col within fragment
    const int rg = lane >> 4;      // C row group
    float cq[4];
    int   cg[4];
    #pragma unroll
    for (int ni = 0; ni < 4; ++ni) {
        cg[ni] = bn + wn * 64 + ni * 16 + cl;
        cq[ni] = psq[cg[ni]];
    }
    #pragma unroll
    for (int mi = 0; mi < 4; ++mi) {
        #pragma unroll
        for (int r = 0; r < 4; ++r) {
            int row = wm * 64 + mi * 16 + rg * 4 + r;
            float best = fmaf(-2.f, acc[mi][0][r], cq[0]);
            unsigned bcol = (unsigned)cg[0];
            #pragma unroll
            for (int ni = 1; ni < 4; ++ni) {
                float d = fmaf(-2.f, acc[mi][ni][r], cq[ni]);
                if (d < best) { best = d; bcol = (unsigned)cg[ni]; }
            }
            unsigned long long key =
                ((unsigned long long)fkey(best) << 32) | (unsigned long long)bcol;
            #pragma unroll
            for (int m = 1; m < 16; m <<= 1)
                key = umin64(key, __shfl_xor(key, m));
            if (cl == 0) red[row][wn] = key;
        }
    }
    __syncthreads();
    if (tid < 128) {
        blockmin[(size_t)(bm + tid) * NBLK + blockIdx.x] =
            umin64(red[tid][0], red[tid][1]);
    }
}

// ------------------- per-row: approx min -> candidate blocks -> exact rescore
__global__ __launch_bounds__(256)
void rescore_kernel(const float* __restrict__ X, const float* __restrict__ P,
                    const float* __restrict__ psq,
                    const unsigned long long* __restrict__ blockmin,
                    float* __restrict__ out) {
    __shared__ unsigned long long rmin[256];
    __shared__ unsigned long long bkey[128];
    __shared__ unsigned cand[256];
    __shared__ float Xs[256];
    __shared__ float part[256];
    __shared__ int cnt;

    const int row = blockIdx.x;
    const int tid = threadIdx.x;

    unsigned long long myk = blockmin[(size_t)row * NBLK + tid];
    rmin[tid] = myk;
    if (tid < 64)
        ((f32x4*)Xs)[tid] = ((const f32x4*)(X + (size_t)row * ND))[tid];
    if (tid == 0) cnt = 0;
    __syncthreads();
    #pragma unroll
    for (int s = 128; s > 0; s >>= 1) {
        if (tid < s) rmin[tid] = umin64(rmin[tid], rmin[tid + s]);
        __syncthreads();
    }
    float dmin = fkey_inv((unsigned)(rmin[0] >> 32));
    unsigned keythr = fkey(dmin + MARGIN);
    if ((unsigned)(myk >> 32) <= keythr) {
        int s = atomicAdd(&cnt, 1);
        cand[s] = (unsigned)tid;
    }
    __syncthreads();

    const int n    = cnt;
    const int colt = tid & 127;
    const int half = tid >> 7;
    unsigned long long best = 0xFFFFFFFFFFFFFFFFull;
    for (int c = 0; c < n; ++c) {
        int col = (int)cand[c] * 128 + colt;
        const f32x4* p4 = (const f32x4*)(P + (size_t)col * ND + half * 128);
        const f32x4* x4 = (const f32x4*)(Xs + half * 128);
        float s = 0.f;
        #pragma unroll 8
        for (int i = 0; i < 32; ++i) {
            f32x4 pv = p4[i], xv = x4[i];
            s = fmaf(xv.x, pv.x, s); s = fmaf(xv.y, pv.y, s);
            s = fmaf(xv.z, pv.z, s); s = fmaf(xv.w, pv.w, s);
        }
        part[tid] = s;
        __syncthreads();
        if (tid < 128) {
            float tot = part[tid] + part[tid + 128];
            float d = fmaf(-2.f, tot, psq[col]);
            unsigned long long k =
                ((unsigned long long)fkey(d) << 32) | (unsigned long long)col;
            best = umin64(best, k);
        }
        __syncthreads();
    }
    if (tid < 128) bkey[tid] = best;
    __syncthreads();
    #pragma unroll
    for (int s = 64; s > 0; s >>= 1) {
        if (tid < s) bkey[tid] = umin64(bkey[tid], bkey[tid + s]);
        __syncthreads();
    }
    unsigned bestcol = (unsigned)(bkey[0] & 0xFFFFFFFFull);
    if (tid < 64)
        ((f32x4*)(out + (size_t)row * ND))[tid] =
            ((const f32x4*)(P + (size_t)bestcol * ND))[tid];
}

// ======================= fallback: round-1 exact fp32 path (small ws) =======
#define BM1 128
#define BN1 128
#define BK1 32
#define LDA1 132

__global__ void psq_init_kernel(const float* __restrict__ P, float* __restrict__ psq,
                                unsigned long long* __restrict__ minpack) {
    int row  = blockIdx.x * 4 + (threadIdx.x >> 6);
    int lane = threadIdx.x & 63;
    float4 p4 = ((const float4*)(P + (size_t)row * ND))[lane];
    float s = p4.x*p4.x + p4.y*p4.y + p4.z*p4.z + p4.w*p4.w;
    #pragma unroll
    for (int off = 32; off > 0; off >>= 1) s += __shfl_down(s, off);
    if (lane == 0) psq[row] = s;
    int gid = blockIdx.x * blockDim.x + threadIdx.x;
    if (gid < NB) minpack[gid] = 0xFFFFFFFFFFFFFFFFull;
}

__global__ __launch_bounds__(256, 2)
void nn_main_kernel(const float* __restrict__ X, const float* __restrict__ P,
                    const float* __restrict__ psq,
                    unsigned long long* __restrict__ minpack) {
    __shared__ __align__(16) char smem_raw[2 * BK1 * LDA1 * 4];
    float (*As)[LDA1] = (float (*)[LDA1])smem_raw;
    float (*Bs)[LDA1] = (float (*)[LDA1])(smem_raw + BK1 * LDA1 * 4);
    const int bm  = blockIdx.y * BM1;
    const int bn  = blockIdx.x * BN1;
    const int tid = threadIdx.x;
    const int tx  = tid & 15;
    const int ty  = tid >> 4;
    float acc[8][8];
    #pragma unroll
    for (int i = 0; i < 8; ++i)
        #pragma unroll
        for (int j = 0; j < 8; ++j) acc[i][j] = 0.f;
    const int lrow = tid >> 3;
    const int lk   = (tid & 7) * 4;
    for (int k0 = 0; k0 < ND; k0 += BK1) {
        #pragma unroll
        for (int p = 0; p < 4; ++p) {
            int r = p * 32 + lrow;
            float4 a = *(const float4*)(X + (size_t)(bm + r) * ND + k0 + lk);
            As[lk+0][r] = a.x; As[lk+1][r] = a.y; As[lk+2][r] = a.z; As[lk+3][r] = a.w;
            float4 b = *(const float4*)(P + (size_t)(bn + r) * ND + k0 + lk);
            Bs[lk+0][r] = b.x; Bs[lk+1][r] = b.y; Bs[lk+2][r] = b.z; Bs[lk+3][r] = b.w;
        }
        __syncthreads();
        #pragma unroll 4
        for (int k = 0; k < BK1; ++k) {
            float4 a0 = *(const float4*)&As[k][ty*8];
            float4 a1 = *(const float4*)&As[k][ty*8 + 4];
            float4 b0 = *(const float4*)&Bs[k][tx*4];
            float4 b1 = *(const float4*)&Bs[k][64 + tx*4];
            float av[8] = {a0.x,a0.y,a0.z,a0.w,a1.x,a1.y,a1.z,a1.w};
            float bv[8] = {b0.x,b0.y,b0.z,b0.w,b1.x,b1.y,b1.z,b1.w};
            #pragma unroll
            for (int i = 0; i < 8; ++i)
                #pragma unroll
                for (int j = 0; j < 8; ++j)
                    acc[i][j] = fmaf(av[i], bv[j], acc[i][j]);
        }
        __syncthreads();
    }
    unsigned long long (*red)[16] = (unsigned long long (*)[16])smem_raw;
    float cj[8];
    int   jglob[8];
    #pragma unroll
    for (int j = 0; j < 8; ++j) {
        int c = (j < 4) ? (tx*4 + j) : (64 + tx*4 + (j - 4));
        jglob[j] = bn + c;
        cj[j]    = psq[bn + c];
    }
    #pragma unroll
    for (int i = 0; i < 8; ++i) {
        float best = 0.f; unsigned bidx = 0u; bool first = true;
        #pragma unroll
        for (int j = 0; j < 8; ++j) {
            float s = fmaf(-2.f, acc[i][j], cj[j]);
            if (first || s < best) { best = s; bidx = (unsigned)jglob[j]; first = false; }
        }
        unsigned u = fkey(best);
        red[ty*8 + i][tx] = ((unsigned long long)u << 32) | (unsigned long long)bidx;
    }
    __syncthreads();
    if (tid < BM1) {
        unsigned long long m = red[tid][0];
        #pragma unroll
        for (int t = 1; t < 16; ++t) m = umin64(m, red[tid][t]);
        atomicMin(&minpack[bm + tid], m);
    }
}

__global__ void gather_kernel(const float* __restrict__ P,
                              const unsigned long long* __restrict__ minpack,
                              float* __restrict__ out) {
    int row = blockIdx.x;
    unsigned idx = (unsigned)(minpack[row] & 0xFFFFFFFFull);
    int lane = threadIdx.x;
    ((float4*)(out + (size_t)row * ND))[lane] =
        ((const float4*)(P + (size_t)idx * ND))[lane];
}

// ------------------------------------------------------------------- launch
extern "C" void kernel_launch(void* const* d_in, const int* in_sizes, int n_in,
                              void* d_out, int out_size, void* d_ws, size_t ws_size,
                              hipStream_t stream) {
    const float* X = (const float*)d_in[0];
    const float* P = (const float*)d_in[1];
    float* out = (float*)d_out;
    char* w = (char*)d_ws;

    if (ws_size >= WS_NEED) {
        float* psq = (float*)(w + OFF_PSQ);
        __bf16* Xb = (__bf16*)(w + OFF_XB);
        __bf16* Pb = (__bf16*)(w + OFF_PB);
        unsigned long long* blockmin = (unsigned long long*)(w + OFF_BM);

        prep_kernel<<<(NP + NB) / 4, 256, 0, stream>>>(X, P, psq, Xb, Pb);
        dim3 grid(NBLK, NB / 128);   // 256 x 32
        nn_bf16_kernel<<<grid, dim3(256), 0, stream>>>(Xb, Pb, psq, blockmin);
        rescore_kernel<<<NB, 256, 0, stream>>>(X, P, psq, blockmin, out);
    } else {
        float* psq = (float*)w;
        unsigned long long* minpack = (unsigned long long*)(w + (size_t)NP * 4);
        psq_init_kernel<<<NP / 4, 256, 0, stream>>>(P, psq, minpack);
        dim3 grid(NP / BN1, NB / BM1);
        nn_main_kernel<<<grid, dim3(256), 0, stream>>>(X, P, psq, minpack);
        gather_kernel<<<NB, 64, 0, stream>>>(P, minpack, out);
    }
}

// Round 3
// 210.846 us; speedup vs baseline: 3.6618x; 1.3502x over previous
//
#include <hip/hip_runtime.h>
#include <stdint.h>

// L2 1-NN, B=4096 x[B,256] vs N=32768 P[N,256] fp32.
// Round 3: 256x256-tile bf16 MFMA screen (2-phase dbuf pipeline) +
//          64-col-granularity u32 blockmin + slim fp32 margin rescore.
// argmin_j (psq[j] - 2 x.p_j); x_sq drops out. Candidate set
// {64-col groups with approx groupmin <= approx_min + MARGIN} provably
// contains the exact argmin (MARGIN >= 2*max bf16 screening error ~0.7).

#define NB 4096
#define NP 32768
#define ND 256
#define NG 512             // N / 64 column groups
#define MARGIN 2.0f

typedef __attribute__((ext_vector_type(8))) __bf16 bf16x8;
typedef __attribute__((ext_vector_type(4))) __bf16 bf16x4;
typedef __attribute__((ext_vector_type(4))) float f32x4;

// ---- workspace layout (bytes) ----
static constexpr size_t OFF_PSQ = 0;                               // 32768 f32
static constexpr size_t OFF_XB  = 131072;                          // 4096x256 bf16
static constexpr size_t OFF_PB  = OFF_XB + (size_t)NB * ND * 2;    // 32768x256 bf16
static constexpr size_t OFF_BM  = OFF_PB + (size_t)NP * ND * 2;    // 4096x512 u32
static constexpr size_t WS_NEED = OFF_BM + (size_t)NB * NG * 4;    // 27,394,048

__device__ __forceinline__ void gload_lds16(const void* g, void* l) {
    __builtin_amdgcn_global_load_lds(
        (const __attribute__((address_space(1))) uint32_t*)g,
        (__attribute__((address_space(3))) uint32_t*)l, 16, 0, 0);
}
__device__ __forceinline__ unsigned fkey(float f) {
    unsigned u = __float_as_uint(f);
    return (u & 0x80000000u) ? ~u : (u | 0x80000000u);
}
__device__ __forceinline__ float fkey_inv(unsigned u) {
    unsigned o = (u & 0x80000000u) ? (u & 0x7FFFFFFFu) : ~u;
    return __uint_as_float(o);
}
__device__ __forceinline__ unsigned long long umin64(unsigned long long a,
                                                     unsigned long long b) {
    return a < b ? a : b;
}
__device__ __forceinline__ unsigned umin32(unsigned a, unsigned b) {
    return a < b ? a : b;
}

// ------------------------------------------------- prep: bf16 convert + psq
__global__ void prep_kernel(const float* __restrict__ X, const float* __restrict__ P,
                            float* __restrict__ psq, __bf16* __restrict__ Xb,
                            __bf16* __restrict__ Pb) {
    int row  = blockIdx.x * 4 + (threadIdx.x >> 6);  // one wave per row
    int lane = threadIdx.x & 63;
    if (row < NP) {
        f32x4 v = ((const f32x4*)(P + (size_t)row * ND))[lane];
        bf16x4 b;
        b.x = (__bf16)v.x; b.y = (__bf16)v.y; b.z = (__bf16)v.z; b.w = (__bf16)v.w;
        ((bf16x4*)(Pb + (size_t)row * ND))[lane] = b;
        float s = v.x*v.x + v.y*v.y + v.z*v.z + v.w*v.w;
        #pragma unroll
        for (int off = 32; off > 0; off >>= 1) s += __shfl_down(s, off);
        if (lane == 0) psq[row] = s;
    } else {
        int r = row - NP;   // < NB
        f32x4 v = ((const f32x4*)(X + (size_t)r * ND))[lane];
        bf16x4 b;
        b.x = (__bf16)v.x; b.y = (__bf16)v.y; b.z = (__bf16)v.z; b.w = (__bf16)v.w;
        ((bf16x4*)(Xb + (size_t)r * ND))[lane] = b;
    }
}

// --------------------------- 256x256 bf16 MFMA tile + per-(row,64col) min ----
// LDS lane-linear chunks of 16B: chunk c = (frag*2 + ks)*64 + (kg*16 + fr)
//   frag: 16-row group (0..15), ks: k-half of 32 (0..1), kg: k-granule of 8,
//   fr: row within frag. Staging pre-swizzles the GLOBAL source so LDS stays
//   linear (global_load_lds writes base + lane*16). Proven round 2: 0 conflicts.
__device__ __forceinline__ void stage_tile(const __bf16* __restrict__ Xb,
                                           const __bf16* __restrict__ Pb,
                                           char* As, char* Bs,
                                           int bm, int bn, int k0, int tid) {
    const int wbase = tid & ~63;
    #pragma unroll
    for (int i = 0; i < 4; ++i) {
        const int c  = i * 512 + tid;        // chunk 0..2047
        const int fm = c >> 7;
        const int ks = (c >> 6) & 1;
        const int kg = (c >> 4) & 3;
        const int fr = c & 15;
        const int kk = k0 + ks * 32 + kg * 8;
        gload_lds16(Xb + (size_t)(bm + fm * 16 + fr) * ND + kk,
                    As + (size_t)(i * 512 + wbase) * 16);
        gload_lds16(Pb + (size_t)(bn + fm * 16 + fr) * ND + kk,
                    Bs + (size_t)(i * 512 + wbase) * 16);
    }
}

__device__ __forceinline__ void compute_step(const char* As, const char* Bs,
                                             int wm, int wn, int lane,
                                             f32x4 acc[8][4]) {
    #pragma unroll
    for (int ks = 0; ks < 2; ++ks) {
        bf16x8 a[8], b[4];
        #pragma unroll
        for (int mi = 0; mi < 8; ++mi)
            a[mi] = *(const bf16x8*)(As +
                     (size_t)(((wm * 8 + mi) * 2 + ks) * 64 + lane) * 16);
        #pragma unroll
        for (int ni = 0; ni < 4; ++ni)
            b[ni] = *(const bf16x8*)(Bs +
                     (size_t)(((wn * 4 + ni) * 2 + ks) * 64 + lane) * 16);
        #pragma unroll
        for (int mi = 0; mi < 8; ++mi)
            #pragma unroll
            for (int ni = 0; ni < 4; ++ni)
                acc[mi][ni] = __builtin_amdgcn_mfma_f32_16x16x32_bf16(
                    a[mi], b[ni], acc[mi][ni], 0, 0, 0);
    }
}

__global__ __launch_bounds__(512, 2)
void nn_bf16_kernel(const __bf16* __restrict__ Xb, const __bf16* __restrict__ Pb,
                    const float* __restrict__ psq, unsigned* __restrict__ blockmin) {
    __shared__ __align__(16) char smem[131072];
    char* As0 = smem;
    char* Bs0 = smem + 32768;
    char* As1 = smem + 65536;
    char* Bs1 = smem + 98304;

    const int tid  = threadIdx.x;
    const int lane = tid & 63;
    const int wave = tid >> 6;
    const int wm = wave >> 2, wn = wave & 3;
    const int bm = blockIdx.x * 256;     // consecutive blocks share B-panel (L2)
    const int bn = blockIdx.y * 256;

    f32x4 acc[8][4];
    #pragma unroll
    for (int i = 0; i < 8; ++i)
        #pragma unroll
        for (int j = 0; j < 4; ++j) acc[i][j] = (f32x4){0.f, 0.f, 0.f, 0.f};

    // 2-phase pipeline: stage(t+1) issued BEFORE compute(t); one barrier/step.
    stage_tile(Xb, Pb, As0, Bs0, bm, bn, 0, tid);
    __syncthreads();
    stage_tile(Xb, Pb, As1, Bs1, bm, bn, 64, tid);
    compute_step(As0, Bs0, wm, wn, lane, acc);
    __syncthreads();
    stage_tile(Xb, Pb, As0, Bs0, bm, bn, 128, tid);
    compute_step(As1, Bs1, wm, wn, lane, acc);
    __syncthreads();
    stage_tile(Xb, Pb, As1, Bs1, bm, bn, 192, tid);
    compute_step(As0, Bs0, wm, wn, lane, acc);
    __syncthreads();
    compute_step(As1, Bs1, wm, wn, lane, acc);

    // epilogue: dist = psq - 2*dot; per-row min over this wave's 64 cols,
    // direct store of u32 key to blockmin[row][group]; no LDS, no atomics.
    const int cl = lane & 15;     // C col within fragment
    const int rg = lane >> 4;     // C row group
    float cq[4];
    #pragma unroll
    for (int ni = 0; ni < 4; ++ni) cq[ni] = psq[bn + wn * 64 + ni * 16 + cl];
    const int gidx = blockIdx.y * 4 + wn;
    #pragma unroll
    for (int mi = 0; mi < 8; ++mi) {
        #pragma unroll
        for (int r = 0; r < 4; ++r) {
            int row = bm + wm * 128 + mi * 16 + rg * 4 + r;
            float best = fmaf(-2.f, acc[mi][0][r], cq[0]);
            #pragma unroll
            for (int ni = 1; ni < 4; ++ni)
                best = fminf(best, fmaf(-2.f, acc[mi][ni][r], cq[ni]));
            #pragma unroll
            for (int m = 1; m < 16; m <<= 1)
                best = fminf(best, __shfl_xor(best, m));
            if (cl == 0) blockmin[(size_t)row * NG + gidx] = fkey(best);
        }
    }
}

// ------------- per-row: approx min -> candidate 64-col groups -> fp32 rescore
__global__ __launch_bounds__(256)
void rescore_kernel(const float* __restrict__ X, const float* __restrict__ P,
                    const float* __restrict__ psq,
                    const unsigned* __restrict__ blockmin,
                    float* __restrict__ out) {
    __shared__ float Xs[256];
    __shared__ float part[256];
    __shared__ unsigned keymin[256];
    __shared__ unsigned short cand[NG];
    __shared__ int cnt;
    __shared__ unsigned bcol_s;

    const int row = blockIdx.x;
    const int tid = threadIdx.x;
    const unsigned* bmr = blockmin + (size_t)row * NG;

    unsigned k0 = bmr[tid], k1 = bmr[tid + 256];
    if (tid < 64)
        ((f32x4*)Xs)[tid] = ((const f32x4*)(X + (size_t)row * ND))[tid];
    if (tid == 0) cnt = 0;
    keymin[tid] = umin32(k0, k1);
    __syncthreads();
    #pragma unroll
    for (int s = 128; s > 0; s >>= 1) {
        if (tid < s) keymin[tid] = umin32(keymin[tid], keymin[tid + s]);
        __syncthreads();
    }
    unsigned thr = fkey(fkey_inv(keymin[0]) + MARGIN);
    if (k0 <= thr) cand[atomicAdd(&cnt, 1)] = (unsigned short)tid;
    if (k1 <= thr) cand[atomicAdd(&cnt, 1)] = (unsigned short)(tid + 256);
    __syncthreads();

    const int n     = cnt;
    const int ct    = tid & 63;     // col within group
    const int cpart = tid >> 6;     // k-quarter (64 dims)
    unsigned long long best = 0xFFFFFFFFFFFFFFFFull;
    for (int c = 0; c < n; ++c) {
        int g = cand[c];
        int col = g * 64 + ct;
        const f32x4* p4 = (const f32x4*)(P + (size_t)col * ND + cpart * 64);
        const f32x4* x4 = (const f32x4*)(Xs + cpart * 64);
        float s = 0.f;
        #pragma unroll
        for (int i = 0; i < 16; ++i) {
            f32x4 pv = p4[i], xv = x4[i];
            s = fmaf(xv.x, pv.x, s); s = fmaf(xv.y, pv.y, s);
            s = fmaf(xv.z, pv.z, s); s = fmaf(xv.w, pv.w, s);
        }
        part[tid] = s;
        __syncthreads();
        if (tid < 64) {
            int col2 = g * 64 + tid;
            float tot = part[tid] + part[tid + 64] + part[tid + 128] + part[tid + 192];
            float d = fmaf(-2.f, tot, psq[col2]);
            best = umin64(best, ((unsigned long long)fkey(d) << 32) |
                                (unsigned long long)col2);
        }
        __syncthreads();
    }
    if (tid < 64) {
        #pragma unroll
        for (int m = 1; m < 64; m <<= 1)
            best = umin64(best, __shfl_xor(best, m));
        if (tid == 0) bcol_s = (unsigned)(best & 0xFFFFFFFFull);
    }
    __syncthreads();
    unsigned bc = bcol_s;
    if (tid < 64)
        ((f32x4*)(out + (size_t)row * ND))[tid] =
            ((const f32x4*)(P + (size_t)bc * ND))[tid];
}

// ======================= fallback: exact fp32 path (small ws) ===============
#define BM1 128
#define BN1 128
#define BK1 32
#define LDA1 132

__global__ void psq_init_kernel(const float* __restrict__ P, float* __restrict__ psq,
                                unsigned long long* __restrict__ minpack) {
    int row  = blockIdx.x * 4 + (threadIdx.x >> 6);
    int lane = threadIdx.x & 63;
    float4 p4 = ((const float4*)(P + (size_t)row * ND))[lane];
    float s = p4.x*p4.x + p4.y*p4.y + p4.z*p4.z + p4.w*p4.w;
    #pragma unroll
    for (int off = 32; off > 0; off >>= 1) s += __shfl_down(s, off);
    if (lane == 0) psq[row] = s;
    int gid = blockIdx.x * blockDim.x + threadIdx.x;
    if (gid < NB) minpack[gid] = 0xFFFFFFFFFFFFFFFFull;
}

__global__ __launch_bounds__(256, 2)
void nn_main_kernel(const float* __restrict__ X, const float* __restrict__ P,
                    const float* __restrict__ psq,
                    unsigned long long* __restrict__ minpack) {
    __shared__ __align__(16) char smem_raw[2 * BK1 * LDA1 * 4];
    float (*As)[LDA1] = (float (*)[LDA1])smem_raw;
    float (*Bs)[LDA1] = (float (*)[LDA1])(smem_raw + BK1 * LDA1 * 4);
    const int bm  = blockIdx.y * BM1;
    const int bn  = blockIdx.x * BN1;
    const int tid = threadIdx.x;
    const int tx  = tid & 15;
    const int ty  = tid >> 4;
    float acc[8][8];
    #pragma unroll
    for (int i = 0; i < 8; ++i)
        #pragma unroll
        for (int j = 0; j < 8; ++j) acc[i][j] = 0.f;
    const int lrow = tid >> 3;
    const int lk   = (tid & 7) * 4;
    for (int k0 = 0; k0 < ND; k0 += BK1) {
        #pragma unroll
        for (int p = 0; p < 4; ++p) {
            int r = p * 32 + lrow;
            float4 a = *(const float4*)(X + (size_t)(bm + r) * ND + k0 + lk);
            As[lk+0][r] = a.x; As[lk+1][r] = a.y; As[lk+2][r] = a.z; As[lk+3][r] = a.w;
            float4 b = *(const float4*)(P + (size_t)(bn + r) * ND + k0 + lk);
            Bs[lk+0][r] = b.x; Bs[lk+1][r] = b.y; Bs[lk+2][r] = b.z; Bs[lk+3][r] = b.w;
        }
        __syncthreads();
        #pragma unroll 4
        for (int k = 0; k < BK1; ++k) {
            float4 a0 = *(const float4*)&As[k][ty*8];
            float4 a1 = *(const float4*)&As[k][ty*8 + 4];
            float4 b0 = *(const float4*)&Bs[k][tx*4];
            float4 b1 = *(const float4*)&Bs[k][64 + tx*4];
            float av[8] = {a0.x,a0.y,a0.z,a0.w,a1.x,a1.y,a1.z,a1.w};
            float bv[8] = {b0.x,b0.y,b0.z,b0.w,b1.x,b1.y,b1.z,b1.w};
            #pragma unroll
            for (int i = 0; i < 8; ++i)
                #pragma unroll
                for (int j = 0; j < 8; ++j)
                    acc[i][j] = fmaf(av[i], bv[j], acc[i][j]);
        }
        __syncthreads();
    }
    unsigned long long (*red)[16] = (unsigned long long (*)[16])smem_raw;
    float cj[8];
    int   jglob[8];
    #pragma unroll
    for (int j = 0; j < 8; ++j) {
        int c = (j < 4) ? (tx*4 + j) : (64 + tx*4 + (j - 4));
        jglob[j] = bn + c;
        cj[j]    = psq[bn + c];
    }
    #pragma unroll
    for (int i = 0; i < 8; ++i) {
        float best = 0.f; unsigned bidx = 0u; bool first = true;
        #pragma unroll
        for (int j = 0; j < 8; ++j) {
            float s = fmaf(-2.f, acc[i][j], cj[j]);
            if (first || s < best) { best = s; bidx = (unsigned)jglob[j]; first = false; }
        }
        unsigned u = fkey(best);
        red[ty*8 + i][tx] = ((unsigned long long)u << 32) | (unsigned long long)bidx;
    }
    __syncthreads();
    if (tid < BM1) {
        unsigned long long m = red[tid][0];
        #pragma unroll
        for (int t = 1; t < 16; ++t) m = umin64(m, red[tid][t]);
        atomicMin(&minpack[bm + tid], m);
    }
}

__global__ void gather_kernel(const float* __restrict__ P,
                              const unsigned long long* __restrict__ minpack,
                              float* __restrict__ out) {
    int row = blockIdx.x;
    unsigned idx = (unsigned)(minpack[row] & 0xFFFFFFFFull);
    int lane = threadIdx.x;
    ((float4*)(out + (size_t)row * ND))[lane] =
        ((const float4*)(P + (size_t)idx * ND))[lane];
}

// ------------------------------------------------------------------- launch
extern "C" void kernel_launch(void* const* d_in, const int* in_sizes, int n_in,
                              void* d_out, int out_size, void* d_ws, size_t ws_size,
                              hipStream_t stream) {
    const float* X = (const float*)d_in[0];
    const float* P = (const float*)d_in[1];
    float* out = (float*)d_out;
    char* w = (char*)d_ws;

    if (ws_size >= WS_NEED) {
        float* psq = (float*)(w + OFF_PSQ);
        __bf16* Xb = (__bf16*)(w + OFF_XB);
        __bf16* Pb = (__bf16*)(w + OFF_PB);
        unsigned* blockmin = (unsigned*)(w + OFF_BM);

        prep_kernel<<<(NP + NB) / 4, 256, 0, stream>>>(X, P, psq, Xb, Pb);
        dim3 grid(NB / 256, NP / 256);   // 16 x 128; consecutive blocks share B-panel
        nn_bf16_kernel<<<grid, dim3(512), 0, stream>>>(Xb, Pb, psq, blockmin);
        rescore_kernel<<<NB, 256, 0, stream>>>(X, P, psq, blockmin, out);
    } else {
        float* psq = (float*)w;
        unsigned long long* minpack = (unsigned long long*)(w + (size_t)NP * 4);
        psq_init_kernel<<<NP / 4, 256, 0, stream>>>(P, psq, minpack);
        dim3 grid(NP / BN1, NB / BM1);
        nn_main_kernel<<<grid, dim3(256), 0, stream>>>(X, P, psq, minpack);
        gather_kernel<<<NB, 64, 0, stream>>>(P, minpack, out);
    }
}